// Round 8
// baseline (7097.365 us; speedup 1.0000x reference)
//
#include <hip/hip_runtime.h>
#include <cstdint>
#include <cstddef>

// ---------------------------------------------------------------------------
// PCFG-RNN forward on MI355X — round 6 design (resubmit; broker timeouts).
// Weight-stationary restructure: chart GEMVs no longer re-read weights per
// cell (15 GB of L2/L3 traffic, the measured r5 bottleneck). Rows live in
// registers, cells (C=16 per group) stream through LDS. Score dots for level
// l+1 precomputed in D(l) so each level keeps exactly 2 grid barriers.
// ---------------------------------------------------------------------------

#define NBLK 256
#define NTHR 1024
#define LEXB 16
#define CC   16
#define HH   512
#define H3   1536
#define NTOK 64
#define VOCAB 50257
#define NCELLS 2080

// ---- ws layout (float offsets) ----
#define OFF_LP      0                          // 64*64 chart log-probs (zeroed)
#define OFF_H0      4096                       // 512 zeros
#define OFF_GILEX   4608                       // 64*1536
#define OFF_LEXH    (OFF_GILEX + NTOK*H3)      // 64*512
#define OFF_ROWMAX  (OFF_LEXH + NTOK*HH)       // 64 (ordered-uint)
#define OFF_SYNC    (OFF_ROWMAX + 64)          // [0,1]=global [2,3]=lex
#define OFF_SCDOT   (OFF_SYNC + 64)            // 64*64 precomputed logsig dots
#define OFF_CELLH   (OFF_SCDOT + 4096)
#define OFF_CELLGR  (OFF_CELLH  + NCELLS*HH)
#define OFF_CELLHA  (OFF_CELLGR + NCELLS*HH)
#define OFF_CELLGIW (OFF_CELLHA + NCELLS*HH)
#define OFF_CELLGHA (OFF_CELLGIW + NCELLS*H3)
#define WS_FLOATS   (OFF_CELLGHA + NCELLS*H3)  // ~38.9 MB

__device__ __forceinline__ int cid(int i, int j) { return ((j*(j+1)) >> 1) + i; }
__device__ __forceinline__ float sigf(float x) { return 1.f / (1.f + expf(-x)); }
__device__ __forceinline__ float logsigf(float x) {
  return fminf(x, 0.f) - log1pf(expf(-fabsf(x)));
}
__device__ __forceinline__ float wredsum(float s) {
#pragma unroll
  for (int off = 32; off >= 1; off >>= 1) s += __shfl_xor(s, off);
  return s;
}

// 512-dot: register-held row slices vs LDS h; result on all lanes
__device__ __forceinline__ float rowdot(const float4& w0, const float4& w1,
                                        const float* __restrict__ h) {
  const int lane = threadIdx.x & 63;
  const float4* h4 = (const float4*)h;
  float4 a = h4[lane], b = h4[lane + 64];
  float s = w0.x*a.x + w0.y*a.y + w0.z*a.z + w0.w*a.w
          + w1.x*b.x + w1.y*b.y + w1.z*b.z + w1.w*b.w;
  return wredsum(s);
}

// 512-dot, both operands global
__device__ __forceinline__ float dot512(const float* __restrict__ a,
                                        const float* __restrict__ b) {
  const int lane = threadIdx.x & 63;
  const float4* a4 = (const float4*)a;
  const float4* b4 = (const float4*)b;
  float4 x0 = a4[lane], x1 = a4[lane + 64];
  float4 y0 = b4[lane], y1 = b4[lane + 64];
  float s = x0.x*y0.x + x0.y*y0.y + x0.z*y0.z + x0.w*y0.w
          + x1.x*y1.x + x1.y*y1.y + x1.z*y1.z + x1.w*y1.w;
  return wredsum(s);
}

// grid barrier over n blocks (acq/rel atomics only)
__device__ __forceinline__ void gbarN(int* cnt, int* gen, int n) {
  __syncthreads();
  if (threadIdx.x == 0) {
    int g = __hip_atomic_load(gen, __ATOMIC_RELAXED, __HIP_MEMORY_SCOPE_AGENT);
    int p = __hip_atomic_fetch_add(cnt, 1, __ATOMIC_ACQ_REL, __HIP_MEMORY_SCOPE_AGENT);
    if (p == n - 1) {
      __hip_atomic_store(cnt, 0, __ATOMIC_RELAXED, __HIP_MEMORY_SCOPE_AGENT);
      __hip_atomic_store(gen, g + 1, __ATOMIC_RELEASE, __HIP_MEMORY_SCOPE_AGENT);
    } else {
      while (__hip_atomic_load(gen, __ATOMIC_ACQUIRE, __HIP_MEMORY_SCOPE_AGENT) == g)
        __builtin_amdgcn_s_sleep(1);
    }
  }
  __syncthreads();
}

__global__ __launch_bounds__(NTHR, 1) void pcfg_k1(
    const int* __restrict__ tokens, const float* __restrict__ emb,
    const float* __restrict__ lexWih, const float* __restrict__ lexWhh,
    const float* __restrict__ lexbih, const float* __restrict__ lexbhh,
    const float* __restrict__ posW,   const float* __restrict__ posb,
    const float* __restrict__ synWih, const float* __restrict__ synWhh,
    const float* __restrict__ synbih, const float* __restrict__ synbhh,
    const float* __restrict__ composW, float* __restrict__ ws)
{
  __shared__ __align__(16) float sh_h[CC][HH];   // 32 KB cell stage
  __shared__ float sh_gh[96];
  __shared__ int   sh_kb[CC];

  float* lp    = ws + OFF_LP;
  float* h0    = ws + OFF_H0;
  float* gilex = ws + OFF_GILEX;
  float* lexh  = ws + OFF_LEXH;
  unsigned* rowmax = (unsigned*)(ws + OFF_ROWMAX);
  int*   snc   = (int*)(ws + OFF_SYNC);
  float* scdot = ws + OFF_SCDOT;
  float* cH   = ws + OFF_CELLH;
  float* cGR  = ws + OFF_CELLGR;
  float* cHA  = ws + OFF_CELLHA;
  float* cGIW = ws + OFF_CELLGIW;
  float* cGHA = ws + OFF_CELLGHA;

  const int bid = blockIdx.x, tid = threadIdx.x;
  const int wv = tid >> 6, lane = tid & 63;

  // ---------------- P0: zero lp/h0, rowmax init, gi_lex (rows x 16 tokens) --
  {
    for (int idx = bid*NTHR + tid; idx < OFF_GILEX; idx += NBLK*NTHR) ws[idx] = 0.f;
    if (bid == 0 && tid < 64) rowmax[tid] = 0u;
    const int g = bid >> 6, q = bid & 63;        // G=4 groups, nq=64
    for (int t2 = tid; t2 < CC*(HH/4); t2 += NTHR) {
      int ci = t2 >> 7, idx = t2 & 127;
      int tok = tokens[g*CC + ci];
      ((float4*)sh_h[ci])[idx] = ((const float4*)(emb + (size_t)tok*HH))[idx];
    }
    __syncthreads();
    for (int r = q*24 + wv; r < q*24 + 24; r += 16) {      // RB=24, rows<1536
      const float4* wp = (const float4*)(lexWih + (size_t)r*HH);
      float4 w0 = wp[lane], w1 = wp[lane + 64];
      float bias = lexbih[r];
      for (int ci = 0; ci < CC; ++ci) {
        float v = rowdot(w0, w1, sh_h[ci]);
        if (lane == 0) gilex[(size_t)(g*CC + ci)*H3 + r] = v + bias;
      }
    }
  }
  gbarN(snc, snc + 1, NBLK);

  // ---------------- P1: 64 lex GRU steps, 16 blocks, weights in VGPRs ------
  if (bid < LEXB) {
    float4 wr0[6], wr1[6]; float wb[6];
#pragma unroll
    for (int u = 0; u < 6; ++u) {
      int ri = wv*6 + u, gate = ri >> 5, lcol = ri & 31;
      int row = gate*HH + bid*32 + lcol;
      const float4* wp = (const float4*)(lexWhh + (size_t)row*HH);
      wr0[u] = wp[lane]; wr1[u] = wp[lane + 64];
      wb[u] = lexbhh[row];
    }
    for (int t = 0; t < NTOK; ++t) {
      const float* hp = (t == 0) ? h0 : (lexh + (size_t)(t-1)*HH);
      const float4* hp4 = (const float4*)hp;
      float4 ha = hp4[lane], hb2 = hp4[lane + 64];
#pragma unroll
      for (int u = 0; u < 6; ++u) {
        float s = wr0[u].x*ha.x + wr0[u].y*ha.y + wr0[u].z*ha.z + wr0[u].w*ha.w
                + wr1[u].x*hb2.x + wr1[u].y*hb2.y + wr1[u].z*hb2.z + wr1[u].w*hb2.w;
        s = wredsum(s);
        if (lane == 0) sh_gh[wv*6 + u] = s + wb[u];
      }
      __syncthreads();
      if (tid < 32) {
        int col = bid*32 + tid;
        const float* gi = gilex + (size_t)t*H3;
        float rr = sigf(gi[col]         + sh_gh[tid]);
        float zz = sigf(gi[HH + col]    + sh_gh[32 + tid]);
        float aa = tanhf(gi[2*HH + col] + rr*sh_gh[64 + tid]);
        lexh[(size_t)t*HH + col] = (1.f - zz)*aa + zz*hp[col];
      }
      gbarN(snc + 2, snc + 3, LEXB);
    }
  }
  gbarN(snc, snc + 1, NBLK);   // join

  // ---------------- P2a: syn_hids (posW rows x 16 tokens) ----------------
  {
    const int g = bid >> 6, q = bid & 63;
    for (int t2 = tid; t2 < CC*(HH/4); t2 += NTHR) {
      int ci = t2 >> 7, idx = t2 & 127;
      ((float4*)sh_h[ci])[idx] =
          ((const float4*)(lexh + (size_t)(g*CC + ci)*HH))[idx];
    }
    __syncthreads();
    if (wv < 8) {                                   // RB=8, rows<512
      int r = q*8 + wv;
      const float4* wp = (const float4*)(posW + (size_t)r*HH);
      float4 w0 = wp[lane], w1 = wp[lane + 64];
      float bias = posb[r];
      for (int ci = 0; ci < CC; ++ci) {
        float v = rowdot(w0, w1, sh_h[ci]);
        int tt = g*CC + ci;
        if (lane == 0) cH[(size_t)cid(tt,tt)*HH + r] = v + bias;
      }
    }
  }
  gbarN(snc, snc + 1, NBLK);

  // ---------------- P2b: diag giW + gR ----------------
  {
    const int g = bid >> 6, q = bid & 63;
    for (int t2 = tid; t2 < CC*(HH/4); t2 += NTHR) {
      int ci = t2 >> 7, idx = t2 & 127;
      int tt = g*CC + ci;
      ((float4*)sh_h[ci])[idx] =
          ((const float4*)(cH + (size_t)cid(tt,tt)*HH))[idx];
    }
    __syncthreads();
    for (int r = q*32 + wv; r < q*32 + 32; r += 16) {     // RB=32, rows<2048
      const float* wrow = (r < H3) ? (synWih + (size_t)r*HH)
                                   : (composW + (size_t)(r - H3)*HH);
      const float4* wp = (const float4*)wrow;
      float4 w0 = wp[lane], w1 = wp[lane + 64];
      float bias = (r < H3) ? synbih[r] : 0.f;
      for (int ci = 0; ci < CC; ++ci) {
        float v = rowdot(w0, w1, sh_h[ci]);
        if (lane == 0) {
          int tt = g*CC + ci, cc = cid(tt,tt);
          if (r < H3) cGIW[(size_t)cc*H3 + r] = v + bias;
          else        cGR[(size_t)cc*HH + (r - H3)] = v;
        }
      }
    }
  }
  gbarN(snc, snc + 1, NBLK);

  // ---------------- P2c: diag hAc + ghA, + level-1 score dots ----------------
  {
    const int g = bid >> 6, q = bid & 63;
    for (int t2 = tid; t2 < CC*HH; t2 += NTHR) {
      int ci = t2 >> 9, c = t2 & (HH - 1);
      int tt = g*CC + ci, cc = cid(tt,tt);
      const float* giw = cGIW + (size_t)cc*H3;
      float rr = sigf(giw[c] + synbhh[c]);
      float zz = sigf(giw[HH + c] + synbhh[HH + c]);
      float aa = tanhf(giw[2*HH + c] + rr*synbhh[2*HH + c]);
      float hav = (1.f - zz)*aa;
      sh_h[ci][c] = hav;
      if (q == 0) cHA[(size_t)cc*HH + c] = hav;
    }
    __syncthreads();
    for (int r = q*24 + wv; r < q*24 + 24; r += 16) {     // RB=24, rows<1536
      const float4* wp = (const float4*)(synWhh + (size_t)r*HH);
      float4 w0 = wp[lane], w1 = wp[lane + 64];
      float bias = synbhh[r];
      for (int ci = 0; ci < CC; ++ci) {
        float v = rowdot(w0, w1, sh_h[ci]);
        if (lane == 0) {
          int tt = g*CC + ci;
          cGHA[(size_t)cid(tt,tt)*H3 + r] = v + bias;
        }
      }
    }
    int gw = bid*16 + wv;          // level-1 dots: 63 tasks
    if (gw < 63) {
      float d = dot512(cH + (size_t)cid(gw,gw)*HH,
                       cGR + (size_t)cid(gw+1,gw+1)*HH);
      if (lane == 0) scdot[gw*64] = logsigf(d);
    }
  }
  gbarN(snc, snc + 1, NBLK);

  // ---------------- chart levels: 2 barriers each ----------------
  for (int l = 1; l < NTOK; ++l) {
    const int S = NTOK - l;
    const int C = (S < CC) ? S : CC;
    const int G = (S + C - 1) / C;
    const int nq = NBLK / G;
    const int g = bid / nq, q = bid - g*nq;
    const bool active = (bid < G*nq);
    const int Cg = active ? ((S - g*C < C) ? (S - g*C) : C) : 0;

    if (active) {
      // step1: per-cell argmax from precomputed scdot (wave wv = cell wv)
      if (wv < Cg) {
        int s = g*C + wv, i = s, j = i + l;
        float v = -3.4e38f; int idx = 0;
        if (lane < l) {
          v = scdot[s*64 + lane] + lp[i*64 + (i+lane)] + lp[(i+lane+1)*64 + j];
          idx = lane;
        }
#pragma unroll
        for (int off = 32; off >= 1; off >>= 1) {
          float ov = __shfl_xor(v, off);
          int   oi = __shfl_xor(idx, off);
          if (ov > v || (ov == v && oi < idx)) { v = ov; idx = oi; }
        }
        if (lane == 0) { sh_kb[wv] = idx; if (q == 0) lp[i*64 + j] = v; }
      }
      __syncthreads();
      if (l < NTOK - 1) {
        // step2: hB elementwise (redundant per q-block of the group)
        for (int t2 = tid; t2 < Cg*HH; t2 += NTHR) {
          int ci = t2 >> 9, c = t2 & (HH - 1);
          int s = g*C + ci, j = s + l;
          int kb = sh_kb[ci];
          int c1 = cid(s, s + kb), c2 = cid(s + kb + 1, j), cn = cid(s, j);
          const float* giw2 = cGIW + (size_t)c2*H3;
          const float* gha1 = cGHA + (size_t)c1*H3;
          float rr = sigf(giw2[c] + gha1[c]);
          float zz = sigf(giw2[HH + c] + gha1[HH + c]);
          float aa = tanhf(giw2[2*HH + c] + rr*gha1[2*HH + c]);
          float hbv = (1.f - zz)*aa + zz*cHA[(size_t)c1*HH + c];
          sh_h[ci][c] = hbv;
          if (q == 0) cH[(size_t)cn*HH + c] = hbv;
        }
        __syncthreads();
        // step3: giW + gR rows (stationary) x Cg cells
        const int RB = (2048 + nq - 1) / nq;
        const int rbase = q*RB, rend = (2048 < rbase + RB) ? 2048 : (rbase + RB);
        for (int r = rbase + wv; r < rend; r += 16) {
          const float* wrow = (r < H3) ? (synWih + (size_t)r*HH)
                                       : (composW + (size_t)(r - H3)*HH);
          const float4* wp = (const float4*)wrow;
          float4 w0 = wp[lane], w1 = wp[lane + 64];
          float bias = (r < H3) ? synbih[r] : 0.f;
          for (int ci = 0; ci < Cg; ++ci) {
            float v = rowdot(w0, w1, sh_h[ci]);
            if (lane == 0) {
              int s2 = g*C + ci, cn = cid(s2, s2 + l);
              if (r < H3) cGIW[(size_t)cn*H3 + r] = v + bias;
              else        cGR[(size_t)cn*HH + (r - H3)] = v;
            }
          }
        }
      }
    }
    gbarN(snc, snc + 1, NBLK);

    if (l < NTOK - 1) {
      // D phase: hAc + ghA for the new cells
      if (active) {
        for (int t2 = tid; t2 < Cg*HH; t2 += NTHR) {
          int ci = t2 >> 9, c = t2 & (HH - 1);
          int s = g*C + ci, cn = cid(s, s + l);
          const float* giw = cGIW + (size_t)cn*H3;
          float rr = sigf(giw[c] + synbhh[c]);
          float zz = sigf(giw[HH + c] + synbhh[HH + c]);
          float aa = tanhf(giw[2*HH + c] + rr*synbhh[2*HH + c]);
          float hav = (1.f - zz)*aa;
          sh_h[ci][c] = hav;
          if (q == 0) cHA[(size_t)cn*HH + c] = hav;
        }
        __syncthreads();
        const int RB = (H3 + nq - 1) / nq;
        const int rbase = q*RB, rend = (H3 < rbase + RB) ? H3 : (rbase + RB);
        for (int r = rbase + wv; r < rend; r += 16) {
          const float4* wp = (const float4*)(synWhh + (size_t)r*HH);
          float4 w0 = wp[lane], w1 = wp[lane + 64];
          float bias = synbhh[r];
          for (int ci = 0; ci < Cg; ++ci) {
            float v = rowdot(w0, w1, sh_h[ci]);
            if (lane == 0) {
              int s2 = g*C + ci;
              cGHA[(size_t)cid(s2, s2 + l)*H3 + r] = v + bias;
            }
          }
        }
      }
      // next-level score dots (all blocks, global wave partition)
      {
        const int ln = l + 1, Sn = NTOK - ln;
        const int tasks = Sn * ln;
        for (int t2 = bid*16 + wv; t2 < tasks; t2 += NBLK*16) {
          int s = t2 / ln, m = t2 - s*ln;
          int c1 = cid(s, s + m), c2 = cid(s + m + 1, s + ln);
          float d = dot512(cH + (size_t)c1*HH, cGR + (size_t)c2*HH);
          if (lane == 0) scdot[s*64 + m] = logsigf(d);
        }
      }
      gbarN(snc, snc + 1, NBLK);
    }
  }
}

// ---------------- k2: logits GEMM + column log_softmax ----------------
__global__ __launch_bounds__(256, 1) void pcfg_k2(const float* __restrict__ emb,
                                                  const float* __restrict__ ws,
                                                  float* __restrict__ out)
{
  __shared__ __align__(16) float As[64*68];   // reused as Ts after the k-loop
  __shared__ __align__(16) float Bs[64*68];
  __shared__ float colm[64], coll[64];
  __shared__ float part[4*64];
  float* Ts = As;
  const int tid = threadIdx.x;
  const long vb = (long)blockIdx.x * 64;
  const float* lexh = ws + OFF_LEXH;
  float acc[4][4] = {};
  const int cg = (tid & 15) * 4;
  const int rg = (tid >> 4) * 4;

  for (int kc = 0; kc < HH; kc += 64) {
    __syncthreads();
    for (int e = tid; e < 4096; e += 256) {
      int r = e >> 6, k = e & 63;
      As[r*68 + k] = lexh[(size_t)r*HH + kc + k];
      long v = vb + r;
      Bs[r*68 + k] = (v < VOCAB) ? emb[(size_t)v*HH + kc + k] : 0.f;
    }
    __syncthreads();
#pragma unroll
    for (int k4 = 0; k4 < 16; ++k4) {
      float4 av[4], bv[4];
#pragma unroll
      for (int ii = 0; ii < 4; ++ii) {
        av[ii] = *(const float4*)&As[(rg+ii)*68 + k4*4];
        bv[ii] = *(const float4*)&Bs[(cg+ii)*68 + k4*4];
      }
#pragma unroll
      for (int ii = 0; ii < 4; ++ii)
#pragma unroll
        for (int jj = 0; jj < 4; ++jj)
          acc[ii][jj] += av[ii].x*bv[jj].x + av[ii].y*bv[jj].y
                       + av[ii].z*bv[jj].z + av[ii].w*bv[jj].w;
    }
  }
  __syncthreads();   // As reads done before aliasing as Ts
#pragma unroll
  for (int ii = 0; ii < 4; ++ii)
#pragma unroll
    for (int jj = 0; jj < 4; ++jj)
      Ts[(rg+ii)*68 + (cg+jj)] = acc[ii][jj];
  __syncthreads();

  {
    int c = tid & 63, qq = tid >> 6;
    float m = -1e30f;
    for (int r = qq*16; r < qq*16 + 16; ++r) m = fmaxf(m, Ts[r*68 + c]);
    part[qq*64 + c] = m;
  }
  __syncthreads();
  if (tid < 64)
    colm[tid] = fmaxf(fmaxf(part[tid], part[64+tid]), fmaxf(part[128+tid], part[192+tid]));
  __syncthreads();
  {
    int c = tid & 63, qq = tid >> 6;
    float m = colm[c], ssum = 0.f;
    for (int r = qq*16; r < qq*16 + 16; ++r) ssum += expf(Ts[r*68 + c] - m);
    part[qq*64 + c] = ssum;
  }
  __syncthreads();
  if (tid < 64)
    coll[tid] = logf(part[tid] + part[64+tid] + part[128+tid] + part[192+tid]);
  __syncthreads();

  const int valid = (int)min((long)64, (long)VOCAB - vb);
  {
    int c = tid & 63, qq = tid >> 6;
    for (int r = qq*16; r < qq*16 + 16; ++r) {
      float v = Ts[r*68 + c] - colm[c] - coll[c];
      if (c < valid) out[(size_t)r*VOCAB + vb + c] = v;
    }
  }
  __syncthreads();
  if (tid < 64) {
    int r = tid;
    float m = -1e30f;
    for (int c = 0; c < valid; ++c) m = fmaxf(m, Ts[r*68 + c] - colm[c] - coll[c]);
    unsigned b = __float_as_uint(m);
    unsigned enc = (b & 0x80000000u) ? ~b : (b | 0x80000000u);
    atomicMax((unsigned*)(ws + OFF_ROWMAX) + r, enc);
  }
}

__global__ void pcfg_k3(const float* __restrict__ ws, float* __restrict__ out) {
  const int tid = threadIdx.x;
  const unsigned* rm = (const unsigned*)(ws + OFF_ROWMAX);
  float v = 0.f;
  if (tid < 64) {
    unsigned u = rm[tid];
    unsigned b = (u & 0x80000000u) ? (u ^ 0x80000000u) : ~u;
    v = __uint_as_float(b);
  }
  float s = v;
#pragma unroll
  for (int off = 32; off >= 1; off >>= 1) s += __shfl_xor(s, off);
  if (tid == 0) {
    out[(size_t)NTOK*VOCAB]     = ws[OFF_LP + 63];  // chart_lp[0][63]
    out[(size_t)NTOK*VOCAB + 1] = s;                // sum of per-row maxima
  }
}

extern "C" void kernel_launch(void* const* d_in, const int* in_sizes, int n_in,
                              void* d_out, int out_size, void* d_ws, size_t ws_size,
                              hipStream_t stream) {
  (void)in_sizes; (void)n_in; (void)out_size;
  const int*   tokens = (const int*)  d_in[0];
  const float* emb    = (const float*)d_in[1];
  const float* lexWih = (const float*)d_in[2];
  const float* lexWhh = (const float*)d_in[3];
  const float* lexbih = (const float*)d_in[4];
  const float* lexbhh = (const float*)d_in[5];
  const float* posW   = (const float*)d_in[6];
  const float* posb   = (const float*)d_in[7];
  const float* synWih = (const float*)d_in[8];
  const float* synWhh = (const float*)d_in[9];
  const float* synbih = (const float*)d_in[10];
  const float* synbhh = (const float*)d_in[11];
  const float* composW= (const float*)d_in[12];
  float* ws  = (float*)d_ws;
  float* out = (float*)d_out;

  if (ws_size < (size_t)WS_FLOATS * sizeof(float)) return;

  hipMemsetAsync((char*)d_ws + (size_t)OFF_SYNC * sizeof(float), 0,
                 64 * sizeof(float), stream);
  pcfg_k1<<<NBLK, NTHR, 0, stream>>>(tokens, emb, lexWih, lexWhh, lexbih, lexbhh,
                                     posW, posb, synWih, synWhh, synbih, synbhh,
                                     composW, ws);
  pcfg_k2<<<(VOCAB + 63)/64, 256, 0, stream>>>(emb, ws, out);
  pcfg_k3<<<1, 64, 0, stream>>>(ws, out);
}

// Round 10
// 3061.054 us; speedup vs baseline: 2.3186x; 2.3186x over previous
//
#include <hip/hip_runtime.h>
#include <cstdint>
#include <cstddef>

// ---------------------------------------------------------------------------
// PCFG-RNN forward on MI355X — round 9 design (resubmit; broker timeout).
// Graph-launch sync instead of software grid barriers. r8 post-mortem: 194 sw
// barriers ≈ 30 µs each (atomic contention + cross-XCD spin) = ~85% of k1
// time. Each former barrier-phase is now its own kernel launch
// (hardware-ordered, ~2-5 µs/node in graph replay). Weight-stationary
// internals kept from r8; A/D kernels use paired rowdot2.
// ---------------------------------------------------------------------------

#define NTHR 1024
#define LEXB 16
#define CC   16
#define NQ   64
#define HH   512
#define H3   1536
#define NTOK 64
#define VOCAB 50257
#define NCELLS 2080

// ---- ws layout (float offsets) ----
#define OFF_LP      0
#define OFF_H0      4096
#define OFF_GILEX   4608
#define OFF_LEXH    (OFF_GILEX + NTOK*H3)
#define OFF_ROWMAX  (OFF_LEXH + NTOK*HH)
#define OFF_SYNC    (OFF_ROWMAX + 64)
#define OFF_SCDOT   (OFF_SYNC + 64)
#define OFF_CELLH   (OFF_SCDOT + 4096)
#define OFF_CELLGR  (OFF_CELLH  + NCELLS*HH)
#define OFF_CELLHA  (OFF_CELLGR + NCELLS*HH)
#define OFF_CELLGIW (OFF_CELLHA + NCELLS*HH)
#define OFF_CELLGHA (OFF_CELLGIW + NCELLS*H3)
#define WS_FLOATS   (OFF_CELLGHA + NCELLS*H3)   // ~38.9 MB

__device__ __forceinline__ int cid(int i, int j) { return ((j*(j+1)) >> 1) + i; }
__device__ __forceinline__ float sigf(float x) { return 1.f / (1.f + expf(-x)); }
__device__ __forceinline__ float logsigf(float x) {
  return fminf(x, 0.f) - log1pf(expf(-fabsf(x)));
}
__device__ __forceinline__ float wredsum(float s) {
#pragma unroll
  for (int off = 32; off >= 1; off >>= 1) s += __shfl_xor(s, off);
  return s;
}

__device__ __forceinline__ float rowdot(const float4& w0, const float4& w1,
                                        const float* __restrict__ h) {
  const int lane = threadIdx.x & 63;
  const float4* h4 = (const float4*)h;
  float4 a = h4[lane], b = h4[lane + 64];
  float s = w0.x*a.x + w0.y*a.y + w0.z*a.z + w0.w*a.w
          + w1.x*b.x + w1.y*b.y + w1.z*b.z + w1.w*b.w;
  return wredsum(s);
}

// two rows share the LDS h reads and one paired shuffle-reduction chain
__device__ __forceinline__ void rowdot2(const float4& wa0, const float4& wa1,
                                        const float4& wb0, const float4& wb1,
                                        const float* __restrict__ h,
                                        float& ra, float& rb) {
  const int lane = threadIdx.x & 63;
  const float4* h4 = (const float4*)h;
  float4 x = h4[lane], y = h4[lane + 64];
  float sa = wa0.x*x.x + wa0.y*x.y + wa0.z*x.z + wa0.w*x.w
           + wa1.x*y.x + wa1.y*y.y + wa1.z*y.z + wa1.w*y.w;
  float sb = wb0.x*x.x + wb0.y*x.y + wb0.z*x.z + wb0.w*x.w
           + wb1.x*y.x + wb1.y*y.y + wb1.z*y.z + wb1.w*y.w;
#pragma unroll
  for (int off = 32; off >= 1; off >>= 1) {
    sa += __shfl_xor(sa, off);
    sb += __shfl_xor(sb, off);
  }
  ra = sa; rb = sb;
}

__device__ __forceinline__ float dot512(const float* __restrict__ a,
                                        const float* __restrict__ b) {
  const int lane = threadIdx.x & 63;
  const float4* a4 = (const float4*)a;
  const float4* b4 = (const float4*)b;
  float4 x0 = a4[lane], x1 = a4[lane + 64];
  float4 y0 = b4[lane], y1 = b4[lane + 64];
  float s = x0.x*y0.x + x0.y*y0.y + x0.z*y0.z + x0.w*y0.w
          + x1.x*y1.x + x1.y*y1.y + x1.z*y1.z + x1.w*y1.w;
  return wredsum(s);
}

// small-N grid barrier (only used by k_lex over 16 co-resident blocks)
__device__ __forceinline__ void gbarN(int* cnt, int* gen, int n) {
  __syncthreads();
  if (threadIdx.x == 0) {
    int g = __hip_atomic_load(gen, __ATOMIC_RELAXED, __HIP_MEMORY_SCOPE_AGENT);
    int p = __hip_atomic_fetch_add(cnt, 1, __ATOMIC_ACQ_REL, __HIP_MEMORY_SCOPE_AGENT);
    if (p == n - 1) {
      __hip_atomic_store(cnt, 0, __ATOMIC_RELAXED, __HIP_MEMORY_SCOPE_AGENT);
      __hip_atomic_store(gen, g + 1, __ATOMIC_RELEASE, __HIP_MEMORY_SCOPE_AGENT);
    } else {
      while (__hip_atomic_load(gen, __ATOMIC_ACQUIRE, __HIP_MEMORY_SCOPE_AGENT) == g)
        __builtin_amdgcn_s_sleep(1);
    }
  }
  __syncthreads();
}

// ---------------- k_init: zero lp/h0, rowmax, gi_lex GEMM ----------------
__global__ __launch_bounds__(NTHR, 1) void k_init(
    const int* __restrict__ tokens, const float* __restrict__ emb,
    const float* __restrict__ lexWih, const float* __restrict__ lexbih,
    float* __restrict__ ws)
{
  __shared__ __align__(16) float sh_h[CC][HH];
  float* gilex = ws + OFF_GILEX;
  unsigned* rowmax = (unsigned*)(ws + OFF_ROWMAX);
  const int bid = blockIdx.x, tid = threadIdx.x;
  const int wv = tid >> 6, lane = tid & 63;

  for (int idx = bid*NTHR + tid; idx < OFF_GILEX; idx += 256*NTHR) ws[idx] = 0.f;
  if (bid == 0 && tid < 64) rowmax[tid] = 0u;

  const int g = bid >> 6, q = bid & 63;
  for (int t2 = tid; t2 < CC*(HH/4); t2 += NTHR) {
    int ci = t2 >> 7, idx = t2 & 127;
    int tok = tokens[g*CC + ci];
    ((float4*)sh_h[ci])[idx] = ((const float4*)(emb + (size_t)tok*HH))[idx];
  }
  __syncthreads();
  for (int r = q*24 + wv; r < q*24 + 24; r += 16) {
    const float4* wp = (const float4*)(lexWih + (size_t)r*HH);
    float4 w0 = wp[lane], w1 = wp[lane + 64];
    float bias = lexbih[r];
    for (int ci = 0; ci < CC; ++ci) {
      float v = rowdot(w0, w1, sh_h[ci]);
      if (lane == 0) gilex[(size_t)(g*CC + ci)*H3 + r] = v + bias;
    }
  }
}

// ---------------- k_lex: 64 sequential GRU steps, weights in VGPRs -------
__global__ __launch_bounds__(NTHR, 1) void k_lex(
    const float* __restrict__ lexWhh, const float* __restrict__ lexbhh,
    float* __restrict__ ws)
{
  __shared__ float sh_gh[96];
  float* h0    = ws + OFF_H0;
  float* gilex = ws + OFF_GILEX;
  float* lexh  = ws + OFF_LEXH;
  int*   snc   = (int*)(ws + OFF_SYNC);
  const int bid = blockIdx.x, tid = threadIdx.x;
  const int wv = tid >> 6, lane = tid & 63;

  float4 wr0[6], wr1[6]; float wb[6];
#pragma unroll
  for (int u = 0; u < 6; ++u) {
    int ri = wv*6 + u, gate = ri >> 5, lcol = ri & 31;
    int row = gate*HH + bid*32 + lcol;
    const float4* wp = (const float4*)(lexWhh + (size_t)row*HH);
    wr0[u] = wp[lane]; wr1[u] = wp[lane + 64];
    wb[u] = lexbhh[row];
  }
  for (int t = 0; t < NTOK; ++t) {
    const float* hp = (t == 0) ? h0 : (lexh + (size_t)(t-1)*HH);
    const float4* hp4 = (const float4*)hp;
    float4 ha = hp4[lane], hb2 = hp4[lane + 64];
#pragma unroll
    for (int u = 0; u < 6; ++u) {
      float s = wr0[u].x*ha.x + wr0[u].y*ha.y + wr0[u].z*ha.z + wr0[u].w*ha.w
              + wr1[u].x*hb2.x + wr1[u].y*hb2.y + wr1[u].z*hb2.z + wr1[u].w*hb2.w;
      s = wredsum(s);
      if (lane == 0) sh_gh[wv*6 + u] = s + wb[u];
    }
    __syncthreads();
    if (tid < 32) {
      int col = bid*32 + tid;
      const float* gi = gilex + (size_t)t*H3;
      float rr = sigf(gi[col]         + sh_gh[tid]);
      float zz = sigf(gi[HH + col]    + sh_gh[32 + tid]);
      float aa = tanhf(gi[2*HH + col] + rr*sh_gh[64 + tid]);
      lexh[(size_t)t*HH + col] = (1.f - zz)*aa + zz*hp[col];
    }
    gbarN(snc + 2, snc + 3, LEXB);
  }
}

// ---------------- k_p2a: syn_hids (posW) ----------------
__global__ __launch_bounds__(NTHR, 1) void k_p2a(
    const float* __restrict__ posW, const float* __restrict__ posb,
    float* __restrict__ ws)
{
  __shared__ __align__(16) float sh_h[CC][HH];
  float* lexh = ws + OFF_LEXH;
  float* cH   = ws + OFF_CELLH;
  const int bid = blockIdx.x, tid = threadIdx.x;
  const int wv = tid >> 6, lane = tid & 63;
  const int g = bid >> 6, q = bid & 63;
  for (int t2 = tid; t2 < CC*(HH/4); t2 += NTHR) {
    int ci = t2 >> 7, idx = t2 & 127;
    ((float4*)sh_h[ci])[idx] =
        ((const float4*)(lexh + (size_t)(g*CC + ci)*HH))[idx];
  }
  __syncthreads();
  if (wv < 8) {
    int r = q*8 + wv;
    const float4* wp = (const float4*)(posW + (size_t)r*HH);
    float4 w0 = wp[lane], w1 = wp[lane + 64];
    float bias = posb[r];
    for (int ci = 0; ci < CC; ++ci) {
      float v = rowdot(w0, w1, sh_h[ci]);
      int tt = g*CC + ci;
      if (lane == 0) cH[(size_t)cid(tt,tt)*HH + r] = v + bias;
    }
  }
}

// ---------------- k_p2b: diag giW + gR ----------------
__global__ __launch_bounds__(NTHR, 1) void k_p2b(
    const float* __restrict__ synWih, const float* __restrict__ synbih,
    const float* __restrict__ composW, float* __restrict__ ws)
{
  __shared__ __align__(16) float sh_h[CC][HH];
  float* cH   = ws + OFF_CELLH;
  float* cGR  = ws + OFF_CELLGR;
  float* cGIW = ws + OFF_CELLGIW;
  const int bid = blockIdx.x, tid = threadIdx.x;
  const int wv = tid >> 6, lane = tid & 63;
  const int g = bid >> 6, q = bid & 63;
  for (int t2 = tid; t2 < CC*(HH/4); t2 += NTHR) {
    int ci = t2 >> 7, idx = t2 & 127;
    int tt = g*CC + ci;
    ((float4*)sh_h[ci])[idx] =
        ((const float4*)(cH + (size_t)cid(tt,tt)*HH))[idx];
  }
  __syncthreads();
  for (int r = q*32 + wv; r < q*32 + 32; r += 16) {
    const float* wrow = (r < H3) ? (synWih + (size_t)r*HH)
                                 : (composW + (size_t)(r - H3)*HH);
    const float4* wp = (const float4*)wrow;
    float4 w0 = wp[lane], w1 = wp[lane + 64];
    float bias = (r < H3) ? synbih[r] : 0.f;
    for (int ci = 0; ci < CC; ++ci) {
      float v = rowdot(w0, w1, sh_h[ci]);
      if (lane == 0) {
        int tt = g*CC + ci, cc = cid(tt,tt);
        if (r < H3) cGIW[(size_t)cc*H3 + r] = v + bias;
        else        cGR[(size_t)cc*HH + (r - H3)] = v;
      }
    }
  }
}

// ---------------- k_p2c: diag hAc + ghA, level-1 scdot ----------------
__global__ __launch_bounds__(NTHR, 1) void k_p2c(
    const float* __restrict__ synWhh, const float* __restrict__ synbhh,
    float* __restrict__ ws)
{
  __shared__ __align__(16) float sh_h[CC][HH];
  float* scdot = ws + OFF_SCDOT;
  float* cH   = ws + OFF_CELLH;
  float* cGR  = ws + OFF_CELLGR;
  float* cHA  = ws + OFF_CELLHA;
  float* cGIW = ws + OFF_CELLGIW;
  float* cGHA = ws + OFF_CELLGHA;
  const int bid = blockIdx.x, tid = threadIdx.x;
  const int wv = tid >> 6, lane = tid & 63;
  const int g = bid >> 6, q = bid & 63;
  for (int t2 = tid; t2 < CC*HH; t2 += NTHR) {
    int ci = t2 >> 9, c = t2 & (HH - 1);
    int tt = g*CC + ci, cc = cid(tt,tt);
    const float* giw = cGIW + (size_t)cc*H3;
    float rr = sigf(giw[c] + synbhh[c]);
    float zz = sigf(giw[HH + c] + synbhh[HH + c]);
    float aa = tanhf(giw[2*HH + c] + rr*synbhh[2*HH + c]);
    float hav = (1.f - zz)*aa;
    sh_h[ci][c] = hav;
    if (q == 0) cHA[(size_t)cc*HH + c] = hav;
  }
  __syncthreads();
  for (int r = q*24 + wv; r < q*24 + 24; r += 16) {
    const float4* wp = (const float4*)(synWhh + (size_t)r*HH);
    float4 w0 = wp[lane], w1 = wp[lane + 64];
    float bias = synbhh[r];
    for (int ci = 0; ci < CC; ++ci) {
      float v = rowdot(w0, w1, sh_h[ci]);
      if (lane == 0) {
        int tt = g*CC + ci;
        cGHA[(size_t)cid(tt,tt)*H3 + r] = v + bias;
      }
    }
  }
  int gw = bid*16 + wv;
  if (gw < 63) {
    float d = dot512(cH + (size_t)cid(gw,gw)*HH,
                     cGR + (size_t)cid(gw+1,gw+1)*HH);
    if (lane == 0) scdot[gw*64] = logsigf(d);
  }
}

// ---------------- k_A: level A-phase (argmax, hB, giW, gR) ----------------
__global__ __launch_bounds__(NTHR, 1) void k_A(
    const float* __restrict__ synWih, const float* __restrict__ synbih,
    const float* __restrict__ composW, float* __restrict__ ws,
    int l, int C)
{
  __shared__ __align__(16) float sh_h[CC][HH];
  __shared__ int sh_kb[CC];
  float* lp    = ws + OFF_LP;
  float* scdot = ws + OFF_SCDOT;
  float* cH   = ws + OFF_CELLH;
  float* cHA  = ws + OFF_CELLHA;
  float* cGR  = ws + OFF_CELLGR;
  float* cGIW = ws + OFF_CELLGIW;
  float* cGHA = ws + OFF_CELLGHA;
  const int bid = blockIdx.x, tid = threadIdx.x;
  const int wv = tid >> 6, lane = tid & 63;
  const int S = NTOK - l;
  const int g = bid >> 6, q = bid & 63;
  const int Cg = (S - g*C < C) ? (S - g*C) : C;

  if (wv < Cg) {
    int s = g*C + wv, i = s, j = i + l;
    float v = -3.4e38f; int idx = 0;
    if (lane < l) {
      v = scdot[s*64 + lane] + lp[i*64 + (i+lane)] + lp[(i+lane+1)*64 + j];
      idx = lane;
    }
#pragma unroll
    for (int off = 32; off >= 1; off >>= 1) {
      float ov = __shfl_xor(v, off);
      int   oi = __shfl_xor(idx, off);
      if (ov > v || (ov == v && oi < idx)) { v = ov; idx = oi; }
    }
    if (lane == 0) { sh_kb[wv] = idx; if (q == 0) lp[i*64 + j] = v; }
  }
  __syncthreads();
  if (l >= NTOK - 1) return;

  // hB elementwise into LDS (redundant per q; q==0 writes cH)
  for (int t2 = tid; t2 < Cg*HH; t2 += NTHR) {
    int ci = t2 >> 9, c = t2 & (HH - 1);
    int s = g*C + ci, j = s + l;
    int kb = sh_kb[ci];
    int c1 = cid(s, s + kb), c2 = cid(s + kb + 1, j), cn = cid(s, j);
    const float* giw2 = cGIW + (size_t)c2*H3;
    const float* gha1 = cGHA + (size_t)c1*H3;
    float rr = sigf(giw2[c] + gha1[c]);
    float zz = sigf(giw2[HH + c] + gha1[HH + c]);
    float aa = tanhf(giw2[2*HH + c] + rr*gha1[2*HH + c]);
    float hbv = (1.f - zz)*aa + zz*cHA[(size_t)c1*HH + c];
    sh_h[ci][c] = hbv;
    if (q == 0) cH[(size_t)cn*HH + c] = hbv;
  }
  __syncthreads();

  // giW + gR: rows [q*32, q*32+32) — wave wv owns rows r0=q*32+wv, r1=r0+16.
  // 1536 is a multiple of 32, so a block never straddles the synWih/composW split.
  {
    const int r0 = q*32 + wv, r1 = r0 + 16;
    const bool ih = (r0 < H3);
    const float* wrowA = ih ? (synWih + (size_t)r0*HH) : (composW + (size_t)(r0-H3)*HH);
    const float* wrowB = ih ? (synWih + (size_t)r1*HH) : (composW + (size_t)(r1-H3)*HH);
    const float4* wpa = (const float4*)wrowA;
    const float4* wpb = (const float4*)wrowB;
    float4 wa0 = wpa[lane], wa1 = wpa[lane + 64];
    float4 wb0 = wpb[lane], wb1 = wpb[lane + 64];
    float biasA = ih ? synbih[r0] : 0.f;
    float biasB = ih ? synbih[r1] : 0.f;
    for (int ci = 0; ci < Cg; ++ci) {
      float va, vb;
      rowdot2(wa0, wa1, wb0, wb1, sh_h[ci], va, vb);
      if (lane == 0) {
        int s2 = g*C + ci, cn = cid(s2, s2 + l);
        if (ih) {
          cGIW[(size_t)cn*H3 + r0] = va + biasA;
          cGIW[(size_t)cn*H3 + r1] = vb + biasB;
        } else {
          cGR[(size_t)cn*HH + (r0 - H3)] = va;
          cGR[(size_t)cn*HH + (r1 - H3)] = vb;
        }
      }
    }
  }
}

// ---------------- k_D: level D-phase (hAc, ghA, scdot(l+1)) ----------------
__global__ __launch_bounds__(NTHR, 1) void k_D(
    const float* __restrict__ synWhh, const float* __restrict__ synbhh,
    float* __restrict__ ws, int l, int C)
{
  __shared__ __align__(16) float sh_h[CC][HH];
  float* scdot = ws + OFF_SCDOT;
  float* cH   = ws + OFF_CELLH;
  float* cGR  = ws + OFF_CELLGR;
  float* cHA  = ws + OFF_CELLHA;
  float* cGIW = ws + OFF_CELLGIW;
  float* cGHA = ws + OFF_CELLGHA;
  const int bid = blockIdx.x, tid = threadIdx.x;
  const int wv = tid >> 6, lane = tid & 63;
  const int S = NTOK - l;
  const int g = bid >> 6, q = bid & 63;
  const int Cg = (S - g*C < C) ? (S - g*C) : C;

  for (int t2 = tid; t2 < Cg*HH; t2 += NTHR) {
    int ci = t2 >> 9, c = t2 & (HH - 1);
    int s = g*C + ci, cn = cid(s, s + l);
    const float* giw = cGIW + (size_t)cn*H3;
    float rr = sigf(giw[c] + synbhh[c]);
    float zz = sigf(giw[HH + c] + synbhh[HH + c]);
    float aa = tanhf(giw[2*HH + c] + rr*synbhh[2*HH + c]);
    float hav = (1.f - zz)*aa;
    sh_h[ci][c] = hav;
    if (q == 0) cHA[(size_t)cn*HH + c] = hav;
  }
  __syncthreads();

  // ghA: rows [q*24, q*24+24) — waves 0..11 own pairs (r0, r0+12)
  if (wv < 12) {
    const int r0 = q*24 + wv, r1 = r0 + 12;
    const float4* wpa = (const float4*)(synWhh + (size_t)r0*HH);
    const float4* wpb = (const float4*)(synWhh + (size_t)r1*HH);
    float4 wa0 = wpa[lane], wa1 = wpa[lane + 64];
    float4 wb0 = wpb[lane], wb1 = wpb[lane + 64];
    float biasA = synbhh[r0], biasB = synbhh[r1];
    for (int ci = 0; ci < Cg; ++ci) {
      float va, vb;
      rowdot2(wa0, wa1, wb0, wb1, sh_h[ci], va, vb);
      if (lane == 0) {
        int s2 = g*C + ci, cn = cid(s2, s2 + l);
        cGHA[(size_t)cn*H3 + r0] = va + biasA;
        cGHA[(size_t)cn*H3 + r1] = vb + biasB;
      }
    }
  }

  // scdot for level l+1 (reads cH/cGR of levels <= l, all visible)
  {
    const int ln = l + 1, Sn = NTOK - ln;
    const int tasks = Sn * ln;
    for (int t2 = bid*16 + wv; t2 < tasks; t2 += (int)gridDim.x*16) {
      int s = t2 / ln, m = t2 - s*ln;
      int c1 = cid(s, s + m), c2 = cid(s + m + 1, s + ln);
      float d = dot512(cH + (size_t)c1*HH, cGR + (size_t)c2*HH);
      if (lane == 0) scdot[s*64 + m] = logsigf(d);
    }
  }
}

// ---------------- k2: logits GEMM + column log_softmax ----------------
__global__ __launch_bounds__(256, 1) void pcfg_k2(const float* __restrict__ emb,
                                                  const float* __restrict__ ws,
                                                  float* __restrict__ out)
{
  __shared__ __align__(16) float As[64*68];
  __shared__ __align__(16) float Bs[64*68];
  __shared__ float colm[64], coll[64];
  __shared__ float part[4*64];
  float* Ts = As;
  const int tid = threadIdx.x;
  const long vb = (long)blockIdx.x * 64;
  const float* lexh = ws + OFF_LEXH;
  float acc[4][4] = {};
  const int cg = (tid & 15) * 4;
  const int rg = (tid >> 4) * 4;

  for (int kc = 0; kc < HH; kc += 64) {
    __syncthreads();
    for (int e = tid; e < 4096; e += 256) {
      int r = e >> 6, k = e & 63;
      As[r*68 + k] = lexh[(size_t)r*HH + kc + k];
      long v = vb + r;
      Bs[r*68 + k] = (v < VOCAB) ? emb[(size_t)v*HH + kc + k] : 0.f;
    }
    __syncthreads();
#pragma unroll
    for (int k4 = 0; k4 < 16; ++k4) {
      float4 av[4], bv[4];
#pragma unroll
      for (int ii = 0; ii < 4; ++ii) {
        av[ii] = *(const float4*)&As[(rg+ii)*68 + k4*4];
        bv[ii] = *(const float4*)&Bs[(cg+ii)*68 + k4*4];
      }
#pragma unroll
      for (int ii = 0; ii < 4; ++ii)
#pragma unroll
        for (int jj = 0; jj < 4; ++jj)
          acc[ii][jj] += av[ii].x*bv[jj].x + av[ii].y*bv[jj].y
                       + av[ii].z*bv[jj].z + av[ii].w*bv[jj].w;
    }
  }
  __syncthreads();
#pragma unroll
  for (int ii = 0; ii < 4; ++ii)
#pragma unroll
    for (int jj = 0; jj < 4; ++jj)
      Ts[(rg+ii)*68 + (cg+jj)] = acc[ii][jj];
  __syncthreads();

  {
    int c = tid & 63, qq = tid >> 6;
    float m = -1e30f;
    for (int r = qq*16; r < qq*16 + 16; ++r) m = fmaxf(m, Ts[r*68 + c]);
    part[qq*64 + c] = m;
  }
  __syncthreads();
  if (tid < 64)
    colm[tid] = fmaxf(fmaxf(part[tid], part[64+tid]), fmaxf(part[128+tid], part[192+tid]));
  __syncthreads();
  {
    int c = tid & 63, qq = tid >> 6;
    float m = colm[c], ssum = 0.f;
    for (int r = qq*16; r < qq*16 + 16; ++r) ssum += expf(Ts[r*68 + c] - m);
    part[qq*64 + c] = ssum;
  }
  __syncthreads();
  if (tid < 64)
    coll[tid] = logf(part[tid] + part[64+tid] + part[128+tid] + part[192+tid]);
  __syncthreads();

  const int valid = (int)min((long)64, (long)VOCAB - vb);
  {
    int c = tid & 63, qq = tid >> 6;
    for (int r = qq*16; r < qq*16 + 16; ++r) {
      float v = Ts[r*68 + c] - colm[c] - coll[c];
      if (c < valid) out[(size_t)r*VOCAB + vb + c] = v;
    }
  }
  __syncthreads();
  if (tid < 64) {
    int r = tid;
    float m = -1e30f;
    for (int c = 0; c < valid; ++c) m = fmaxf(m, Ts[r*68 + c] - colm[c] - coll[c]);
    unsigned b = __float_as_uint(m);
    unsigned enc = (b & 0x80000000u) ? ~b : (b | 0x80000000u);
    atomicMax((unsigned*)(ws + OFF_ROWMAX) + r, enc);
  }
}

__global__ void pcfg_k3(const float* __restrict__ ws, float* __restrict__ out) {
  const int tid = threadIdx.x;
  const unsigned* rm = (const unsigned*)(ws + OFF_ROWMAX);
  float v = 0.f;
  if (tid < 64) {
    unsigned u = rm[tid];
    unsigned b = (u & 0x80000000u) ? (u ^ 0x80000000u) : ~u;
    v = __uint_as_float(b);
  }
  float s = v;
#pragma unroll
  for (int off = 32; off >= 1; off >>= 1) s += __shfl_xor(s, off);
  if (tid == 0) {
    out[(size_t)NTOK*VOCAB]     = ws[OFF_LP + 63];
    out[(size_t)NTOK*VOCAB + 1] = s;
  }
}

extern "C" void kernel_launch(void* const* d_in, const int* in_sizes, int n_in,
                              void* d_out, int out_size, void* d_ws, size_t ws_size,
                              hipStream_t stream) {
  (void)in_sizes; (void)n_in; (void)out_size;
  const int*   tokens = (const int*)  d_in[0];
  const float* emb    = (const float*)d_in[1];
  const float* lexWih = (const float*)d_in[2];
  const float* lexWhh = (const float*)d_in[3];
  const float* lexbih = (const float*)d_in[4];
  const float* lexbhh = (const float*)d_in[5];
  const float* posW   = (const float*)d_in[6];
  const float* posb   = (const float*)d_in[7];
  const float* synWih = (const float*)d_in[8];
  const float* synWhh = (const float*)d_in[9];
  const float* synbih = (const float*)d_in[10];
  const float* synbhh = (const float*)d_in[11];
  const float* composW= (const float*)d_in[12];
  float* ws  = (float*)d_ws;
  float* out = (float*)d_out;

  if (ws_size < (size_t)WS_FLOATS * sizeof(float)) return;

  hipMemsetAsync((char*)d_ws + (size_t)OFF_SYNC * sizeof(float), 0,
                 64 * sizeof(float), stream);
  k_init<<<256, NTHR, 0, stream>>>(tokens, emb, lexWih, lexbih, ws);
  k_lex <<<LEXB, NTHR, 0, stream>>>(lexWhh, lexbhh, ws);
  k_p2a <<<256, NTHR, 0, stream>>>(posW, posb, ws);
  k_p2b <<<256, NTHR, 0, stream>>>(synWih, synbih, composW, ws);
  k_p2c <<<256, NTHR, 0, stream>>>(synWhh, synbhh, ws);

  for (int l = 1; l < NTOK; ++l) {
    int S = NTOK - l;
    int C = (S < CC) ? S : CC;
    int G = (S + C - 1) / C;
    k_A<<<G*NQ, NTHR, 0, stream>>>(synWih, synbih, composW, ws, l, C);
    if (l < NTOK - 1)
      k_D<<<G*NQ, NTHR, 0, stream>>>(synWhh, synbhh, ws, l, C);
  }

  pcfg_k2<<<(VOCAB + 63)/64, 256, 0, stream>>>(emb, ws, out);
  pcfg_k3<<<1, 64, 0, stream>>>(ws, out);
}